// Round 3
// baseline (497.955 us; speedup 1.0000x reference)
//
#include <hip/hip_runtime.h>
#include <hip/hip_bf16.h>
#include <cmath>

#define NB 32
#define NS 4096
#define NK 1024
#define ND 512
#define WSTRIDE 1536   // ENC2 + DEC

#define APITCH 40      // u16 per A-tile row (32 payload + 8 pad)
#define BPITCH 40      // u16 per B-tile row

using bf16x8 = __attribute__((ext_vector_type(8))) __bf16;
using f32x4  = __attribute__((ext_vector_type(4))) float;
typedef unsigned short u16;

__device__ inline u16 f2b(float x) {
    __hip_bfloat16 h = __float2bfloat16(x);
    u16 u; __builtin_memcpy(&u, &h, 2); return u;
}

// ---------------------------------------------------------------------------
// Kernel 0: Wc = W_attn[:, 512:] -> bf16, plain row-major [d][e]
__global__ void pack_wc_kernel(const float* __restrict__ W, u16* __restrict__ wcb) {
    int idx = blockIdx.x * 256 + threadIdx.x;   // 512*1024 elements
    int n = idx >> 10, k = idx & 1023;
    wcb[idx] = f2b(W[(size_t)n * WSTRIDE + ND + k]);
}

// ---------------------------------------------------------------------------
// Kernel 1: h_proj[b][d] = bias[d] + sum_k hidden[b][k] * W_attn[d][k]  (f32 exact)
__global__ void hproj_kernel(const float* __restrict__ hidden, const float* __restrict__ W,
                             const float* __restrict__ bias, float* __restrict__ hp) {
    int b = blockIdx.x, d = threadIdx.x;   // 512 threads
    __shared__ float sh[ND];
    sh[d] = hidden[b * ND + d];
    __syncthreads();
    const float4* wr = (const float4*)(W + (size_t)d * WSTRIDE);
    float acc = bias[d];
#pragma unroll 8
    for (int k = 0; k < ND / 4; k++) {
        float4 w4 = wr[k];
        acc += w4.x * sh[4 * k] + w4.y * sh[4 * k + 1] + w4.z * sh[4 * k + 2] + w4.w * sh[4 * k + 3];
    }
    hp[b * ND + d] = acc;
}

// ---------------------------------------------------------------------------
// Kernel 2: fused  c_proj GEMM (bf16 MFMA, f32 acc) + tanh + dot-v -> scores
// Block: 512 threads (8 waves). Tile: BM=64 rows of S, full N=512.
// Wave w owns columns w*64..w*64+63 (4x4 16x16x32 fragments).
// LDS: plain row-major k-contiguous; lane l reads 8 contiguous bf16 at
// [frag*16 + (l&15)][(l>>4)*8] — identical k-slot map for A and B.
__global__ __launch_bounds__(512, 2)
void fused_scores_kernel(const float* __restrict__ ctx, const u16* __restrict__ wcb,
                         const float* __restrict__ hp, const float* __restrict__ vvec,
                         float* __restrict__ scores) {
    __shared__ __align__(16) u16 lA[64 * APITCH];    // 5 KB
    __shared__ __align__(16) u16 lB[512 * BPITCH];   // 40 KB
    __shared__ float shHp[ND];
    __shared__ float shV[ND];
    __shared__ float shSc[8][64];

    int tid = threadIdx.x;
    int blk = blockIdx.x;
    int b  = blk >> 6;          // 64 s-tiles per batch
    int s0 = (blk & 63) << 6;

    shHp[tid] = hp[b * ND + tid];
    shV[tid]  = vvec[tid];

    int lane = tid & 63, wid = tid >> 6;
    int l15 = lane & 15, l4 = lane >> 4;

    // A staging: thread -> (row = tid>>3, quad aq = tid&7): 4 consecutive f32 -> 4 bf16
    int arow = tid >> 3, aq = tid & 7;
    const float4* asrc = (const float4*)(ctx + (size_t)b * NS * NK + (size_t)(s0 + arow) * NK);
    u16* adst = lA + arow * APITCH + aq * 4;

    f32x4 acc[4][4];
    f32x4 zero = {0.f, 0.f, 0.f, 0.f};
#pragma unroll
    for (int r = 0; r < 4; r++)
#pragma unroll
        for (int c = 0; c < 4; c++) acc[r][c] = zero;

    for (int ks = 0; ks < NK / 32; ks++) {
        // --- stage A: global f32 -> bf16 -> LDS (k-contiguous) ---
        float4 av = asrc[ks * 8 + aq];
        ushort4 a4;
        a4.x = f2b(av.x); a4.y = f2b(av.y); a4.z = f2b(av.z); a4.w = f2b(av.w);
        *(ushort4*)adst = a4;
        // --- stage B: prepacked bf16 row-major, 16B granules ---
#pragma unroll
        for (int i = 0; i < 4; i++) {
            int g = i * 512 + tid;              // granule: row = g>>2, slot = g&3
            int row = g >> 2, slot = g & 3;
            bf16x8 bv = *(const bf16x8*)(wcb + (size_t)row * NK + ks * 32 + slot * 8);
            *(bf16x8*)(lB + row * BPITCH + slot * 8) = bv;
        }
        __syncthreads();

        bf16x8 af[4], bfr[4];
#pragma unroll
        for (int r = 0; r < 4; r++)
            af[r] = *(const bf16x8*)(lA + (r * 16 + l15) * APITCH + l4 * 8);
#pragma unroll
        for (int c = 0; c < 4; c++)
            bfr[c] = *(const bf16x8*)(lB + (wid * 64 + c * 16 + l15) * BPITCH + l4 * 8);
#pragma unroll
        for (int r = 0; r < 4; r++)
#pragma unroll
            for (int c = 0; c < 4; c++)
                acc[r][c] = __builtin_amdgcn_mfma_f32_16x16x32_bf16(af[r], bfr[c], acc[r][c], 0, 0, 0);
        __syncthreads();
    }

    // --- epilogue: tanh(c_proj + h_proj) . v , reduce over d ---
    // C/D layout (m89/m91): col = lane&15, row = (lane>>4)*4 + reg.
    float part[4][4];
#pragma unroll
    for (int r = 0; r < 4; r++)
#pragma unroll
        for (int i = 0; i < 4; i++) part[r][i] = 0.f;

#pragma unroll
    for (int r = 0; r < 4; r++) {
#pragma unroll
        for (int c = 0; c < 4; c++) {
            int n = (wid << 6) + (c << 4) + l15;   // global column d
            float hpv = shHp[n], vv = shV[n];
#pragma unroll
            for (int i = 0; i < 4; i++) {
                float x = acc[r][c][i] + hpv;
                part[r][i] += tanhf(x) * vv;       // s-row = r*16 + l4*4 + i
            }
        }
    }

#pragma unroll
    for (int r = 0; r < 4; r++) {
#pragma unroll
        for (int i = 0; i < 4; i++) {
            float p = part[r][i];
            p += __shfl_xor(p, 1); p += __shfl_xor(p, 2);
            p += __shfl_xor(p, 4); p += __shfl_xor(p, 8);
            if (l15 == 0) shSc[wid][(r << 4) + (l4 << 2) + i] = p;
        }
    }
    __syncthreads();
    if (tid < 64) {
        float s = 0.f;
#pragma unroll
        for (int w = 0; w < 8; w++) s += shSc[w][tid];
        scores[(size_t)b * NS + s0 + tid] = s;
    }
}

// ---------------------------------------------------------------------------
// Kernel 3: masked softmax over S per batch row, f32 output (reference dtype)
__global__ void softmax_kernel(const float* __restrict__ scores, const int* __restrict__ mask,
                               float* __restrict__ out) {
    int b = blockIdx.x, tid = threadIdx.x;   // 256 threads, 16 elems each
    __shared__ float red[256];
    float loc[16];
    float mx = -INFINITY;
#pragma unroll
    for (int i = 0; i < 16; i++) {
        int idx = i * 256 + tid;
        float s = scores[b * NS + idx];
        if (mask[b * NS + idx] == 0) s = -INFINITY;
        loc[i] = s;
        mx = fmaxf(mx, s);
    }
    red[tid] = mx; __syncthreads();
    for (int off = 128; off; off >>= 1) { if (tid < off) red[tid] = fmaxf(red[tid], red[tid + off]); __syncthreads(); }
    mx = red[0]; __syncthreads();
    float sum = 0.f;
#pragma unroll
    for (int i = 0; i < 16; i++) { float e = __expf(loc[i] - mx); loc[i] = e; sum += e; }
    red[tid] = sum; __syncthreads();
    for (int off = 128; off; off >>= 1) { if (tid < off) red[tid] += red[tid + off]; __syncthreads(); }
    float inv = 1.f / red[0];
#pragma unroll
    for (int i = 0; i < 16; i++) out[b * NS + i * 256 + tid] = loc[i] * inv;
}

// ---------------------------------------------------------------------------
extern "C" void kernel_launch(void* const* d_in, const int* in_sizes, int n_in,
                              void* d_out, int out_size, void* d_ws, size_t ws_size,
                              hipStream_t stream) {
    const float* hidden  = (const float*)d_in[0];
    const float* context = (const float*)d_in[1];
    const int*   mask    = (const int*)d_in[2];
    const float* W_attn  = (const float*)d_in[3];
    const float* b_attn  = (const float*)d_in[4];
    const float* v       = (const float*)d_in[5];
    float* out           = (float*)d_out;

    char* ws = (char*)d_ws;
    u16*   wcb    = (u16*)ws;                   // 1 MB
    float* hp     = (float*)(ws + (1 << 20));   // 64 KB
    float* scores = (float*)(ws + (1 << 20) + (64 << 10));  // 512 KB

    pack_wc_kernel<<<2048, 256, 0, stream>>>(W_attn, wcb);
    hproj_kernel<<<NB, ND, 0, stream>>>(hidden, W_attn, b_attn, hp);
    fused_scores_kernel<<<NB * 64, 512, 0, stream>>>(context, wcb, hp, v, scores);
    softmax_kernel<<<NB, 256, 0, stream>>>(scores, mask, out);
}

// Round 4
// 335.287 us; speedup vs baseline: 1.4852x; 1.4852x over previous
//
#include <hip/hip_runtime.h>
#include <hip/hip_bf16.h>
#include <cmath>

#define NB 32
#define NS 4096
#define NK 1024
#define ND 512
#define WSTRIDE 1536   // ENC2 + DEC

using bf16x8 = __attribute__((ext_vector_type(8))) __bf16;
using u16x8  = __attribute__((ext_vector_type(8))) unsigned short;
using f32x4  = __attribute__((ext_vector_type(4))) float;
typedef unsigned short u16;

__device__ inline u16 f2b(float x) {
    __hip_bfloat16 h = __float2bfloat16(x);
    u16 u; __builtin_memcpy(&u, &h, 2); return u;
}

__device__ inline float fast_tanh(float x) {
    float xc = fminf(fmaxf(x, -10.f), 10.f);
    float e = __expf(2.f * xc);
    return (e - 1.f) / (e + 1.f);
}

// ---------------------------------------------------------------------------
// Kernel 0: pack Wc = W_attn[:, 512:] -> bf16, pre-permuted so that a LINEAR
// wave copy (global_load_lds) yields the XOR-swizzled LDS image:
//   LDS byte for element (R, k=ks*32+S*8+j) = (R*64 + S*16 + 2j) ^ ((R&7)<<4)
//   => chunk-local u16 index = ((R*4+S)^(R&7))*8 + j, chunk ks is 16384 u16.
__global__ void pack_wc_kernel(const float* __restrict__ W, u16* __restrict__ wcb) {
    int idx = blockIdx.x * 256 + threadIdx.x;   // 512*1024 elements
    int R = idx >> 10, k = idx & 1023;
    float val = W[(size_t)R * WSTRIDE + ND + k];
    int ks = k >> 5, S = (k >> 3) & 3, j = k & 7;
    int g = ((R << 2) + S) ^ (R & 7);           // granule 0..2047 (bijective)
    wcb[(ks << 14) + (g << 3) + j] = f2b(val);
}

// ---------------------------------------------------------------------------
// Kernel 1: h_proj[b][d] = bias[d] + sum_k hidden[b][k] * W_attn[d][k]  (f32 exact)
__global__ void hproj_kernel(const float* __restrict__ hidden, const float* __restrict__ W,
                             const float* __restrict__ bias, float* __restrict__ hp) {
    int b = blockIdx.x, d = threadIdx.x;   // 512 threads
    __shared__ float sh[ND];
    sh[d] = hidden[b * ND + d];
    __syncthreads();
    const float4* wr = (const float4*)(W + (size_t)d * WSTRIDE);
    float acc = bias[d];
#pragma unroll 8
    for (int k = 0; k < ND / 4; k++) {
        float4 w4 = wr[k];
        acc += w4.x * sh[4 * k] + w4.y * sh[4 * k + 1] + w4.z * sh[4 * k + 2] + w4.w * sh[4 * k + 3];
    }
    hp[b * ND + d] = acc;
}

// ---------------------------------------------------------------------------
// Kernel 2: fused c_proj GEMM (bf16 MFMA) + tanh + dot-v -> scores
// Block tile: 128 (s-rows) x 512 (d-cols), BK=32, 512 threads / 8 waves (2Mx4N).
// Wave (wm=wid>>2, wn=wid&3) owns 64x128: frags r=0..3, c=0..7, acc[4][8].
// LDS: 64B rows, XOR swizzle byte^=((row&7)<<4) on BOTH write and read.
// B staged by global_load_lds from the pre-permuted pack (linear dest).
__global__ __launch_bounds__(512, 2)
void fused_scores_kernel(const float* __restrict__ ctx, const u16* __restrict__ wcb,
                         const float* __restrict__ hp, const float* __restrict__ vvec,
                         float* __restrict__ scores) {
    __shared__ __align__(16) char lA[128 * 64];    // 8 KB
    __shared__ __align__(16) char lB[512 * 64];    // 32 KB
    __shared__ float shHp[ND];
    __shared__ float shV[ND];
    __shared__ float shSc[4][128];

    int tid = threadIdx.x;
    int blk = blockIdx.x;             // 1024 blocks
    int b  = blk >> 5;                // 32 M-tiles per batch
    int s0 = (blk & 31) << 7;

    shHp[tid] = hp[b * ND + tid];
    shV[tid]  = vvec[tid];

    int lane = tid & 63, wid = tid >> 6;
    int l15 = lane & 15, l4 = lane >> 4;
    int wm = wid >> 2, wn = wid & 3;

    // A staging: thread -> row = tid>>2 (0..127), quad q = tid&3 (16B = 8 bf16)
    int srow = tid >> 2, q = tid & 3;
    const float4* asrc = (const float4*)(ctx + (size_t)b * NS * NK + (size_t)(s0 + srow) * NK);
    int awbyte = ((srow << 6) + (q << 4)) ^ ((srow & 7) << 4);

    // fragment LDS byte offsets (loop-invariant)
    int aoff[4], boff[8];
#pragma unroll
    for (int r = 0; r < 4; r++) {
        int row = (wm << 6) + (r << 4) + l15;
        aoff[r] = ((row << 6) + (l4 << 4)) ^ ((row & 7) << 4);
    }
#pragma unroll
    for (int c = 0; c < 8; c++) {
        int row = (wn << 7) + (c << 4) + l15;
        boff[c] = ((row << 6) + (l4 << 4)) ^ ((row & 7) << 4);
    }

    f32x4 acc[4][8];
    f32x4 zero = {0.f, 0.f, 0.f, 0.f};
#pragma unroll
    for (int r = 0; r < 4; r++)
#pragma unroll
        for (int c = 0; c < 8; c++) acc[r][c] = zero;

    const char* wcb_bytes = (const char*)wcb;

    for (int ks = 0; ks < NK / 32; ks++) {
        // --- stage B: 4 x global_load_lds width-16 per thread (linear dest) ---
#pragma unroll
        for (int i = 0; i < 4; i++) {
            int gran = (((wid << 2) + i) << 6) + lane;   // 0..2047
            const char* src = wcb_bytes + (ks << 15) + (gran << 4);
            __builtin_amdgcn_global_load_lds(
                (const __attribute__((address_space(1))) void*)src,
                (__attribute__((address_space(3))) void*)(lB + (((wid << 2) + i) << 10)),
                16, 0, 0);
        }
        // --- stage A: 8 f32 -> 8 bf16 -> one 16B swizzled LDS write ---
        float4 v0 = asrc[(ks << 3) + (q << 1)];
        float4 v1 = asrc[(ks << 3) + (q << 1) + 1];
        u16x8 a8;
        a8[0] = f2b(v0.x); a8[1] = f2b(v0.y); a8[2] = f2b(v0.z); a8[3] = f2b(v0.w);
        a8[4] = f2b(v1.x); a8[5] = f2b(v1.y); a8[6] = f2b(v1.z); a8[7] = f2b(v1.w);
        *(u16x8*)(lA + awbyte) = a8;
        __syncthreads();

        bf16x8 af[4], bfr[8];
#pragma unroll
        for (int r = 0; r < 4; r++) af[r] = *(const bf16x8*)(lA + aoff[r]);
#pragma unroll
        for (int c = 0; c < 8; c++) bfr[c] = *(const bf16x8*)(lB + boff[c]);
#pragma unroll
        for (int r = 0; r < 4; r++)
#pragma unroll
            for (int c = 0; c < 8; c++)
                acc[r][c] = __builtin_amdgcn_mfma_f32_16x16x32_bf16(af[r], bfr[c], acc[r][c], 0, 0, 0);
        __syncthreads();
    }

    // --- epilogue: tanh(c_proj + h_proj) . v , reduce over d ---
    // C/D: col = lane&15 (d), row = l4*4 + i (s within frag)
    float part[4][4];
#pragma unroll
    for (int r = 0; r < 4; r++)
#pragma unroll
        for (int i = 0; i < 4; i++) part[r][i] = 0.f;

#pragma unroll
    for (int r = 0; r < 4; r++) {
#pragma unroll
        for (int c = 0; c < 8; c++) {
            int d = (wn << 7) + (c << 4) + l15;
            float hpv = shHp[d], vv = shV[d];
#pragma unroll
            for (int i = 0; i < 4; i++) {
                float x = acc[r][c][i] + hpv;
                part[r][i] += fast_tanh(x) * vv;
            }
        }
    }

#pragma unroll
    for (int r = 0; r < 4; r++) {
#pragma unroll
        for (int i = 0; i < 4; i++) {
            float p = part[r][i];
            p += __shfl_xor(p, 1); p += __shfl_xor(p, 2);
            p += __shfl_xor(p, 4); p += __shfl_xor(p, 8);
            if (l15 == 0) shSc[wn][(wm << 6) + (r << 4) + (l4 << 2) + i] = p;
        }
    }
    __syncthreads();
    if (tid < 128) {
        float s = shSc[0][tid] + shSc[1][tid] + shSc[2][tid] + shSc[3][tid];
        scores[(size_t)b * NS + s0 + tid] = s;
    }
}

// ---------------------------------------------------------------------------
// Kernel 3: masked softmax over S per batch row, f32 output
__global__ void softmax_kernel(const float* __restrict__ scores, const int* __restrict__ mask,
                               float* __restrict__ out) {
    int b = blockIdx.x, tid = threadIdx.x;   // 256 threads, 16 elems each
    __shared__ float red[256];
    float loc[16];
    float mx = -INFINITY;
#pragma unroll
    for (int i = 0; i < 16; i++) {
        int idx = i * 256 + tid;
        float s = scores[b * NS + idx];
        if (mask[b * NS + idx] == 0) s = -INFINITY;
        loc[i] = s;
        mx = fmaxf(mx, s);
    }
    red[tid] = mx; __syncthreads();
    for (int off = 128; off; off >>= 1) { if (tid < off) red[tid] = fmaxf(red[tid], red[tid + off]); __syncthreads(); }
    mx = red[0]; __syncthreads();
    float sum = 0.f;
#pragma unroll
    for (int i = 0; i < 16; i++) { float e = __expf(loc[i] - mx); loc[i] = e; sum += e; }
    red[tid] = sum; __syncthreads();
    for (int off = 128; off; off >>= 1) { if (tid < off) red[tid] += red[tid + off]; __syncthreads(); }
    float inv = 1.f / red[0];
#pragma unroll
    for (int i = 0; i < 16; i++) out[b * NS + i * 256 + tid] = loc[i] * inv;
}

// ---------------------------------------------------------------------------
extern "C" void kernel_launch(void* const* d_in, const int* in_sizes, int n_in,
                              void* d_out, int out_size, void* d_ws, size_t ws_size,
                              hipStream_t stream) {
    const float* hidden  = (const float*)d_in[0];
    const float* context = (const float*)d_in[1];
    const int*   mask    = (const int*)d_in[2];
    const float* W_attn  = (const float*)d_in[3];
    const float* b_attn  = (const float*)d_in[4];
    const float* v       = (const float*)d_in[5];
    float* out           = (float*)d_out;

    char* ws = (char*)d_ws;
    u16*   wcb    = (u16*)ws;                   // 1 MB
    float* hp     = (float*)(ws + (1 << 20));   // 64 KB
    float* scores = (float*)(ws + (1 << 20) + (64 << 10));  // 512 KB

    pack_wc_kernel<<<2048, 256, 0, stream>>>(W_attn, wcb);
    hproj_kernel<<<NB, ND, 0, stream>>>(hidden, W_attn, b_attn, hp);
    fused_scores_kernel<<<NB * 32, 512, 0, stream>>>(context, wcb, hp, v, scores);
    softmax_kernel<<<NB, 256, 0, stream>>>(scores, mask, out);
}

// Round 5
// 299.901 us; speedup vs baseline: 1.6604x; 1.1180x over previous
//
#include <hip/hip_runtime.h>
#include <hip/hip_bf16.h>
#include <cmath>

#define NB 32
#define NS 4096
#define NK 1024
#define ND 512
#define WSTRIDE 1536   // ENC2 + DEC
#define NT 32          // K-steps (BK=32)

using bf16x8 = __attribute__((ext_vector_type(8))) __bf16;
using u16x8  = __attribute__((ext_vector_type(8))) unsigned short;
using f32x4  = __attribute__((ext_vector_type(4))) float;
typedef unsigned short u16;

__device__ inline u16 f2b(float x) {
    __hip_bfloat16 h = __float2bfloat16(x);
    u16 u; __builtin_memcpy(&u, &h, 2); return u;
}

__device__ inline float fast_tanh(float x) {
    float xc = fminf(fmaxf(x, -10.f), 10.f);
    float e = __expf(2.f * xc);
    return (e - 1.f) / (e + 1.f);
}

// ---------------------------------------------------------------------------
// Kernel 0: pack Wc = W_attn[:, 512:] -> bf16, pre-permuted so that a LINEAR
// wave copy (global_load_lds) yields the XOR-swizzled LDS image:
//   chunk ks (16384 u16): element (R, k=ks*32+S*8+j) -> granule g=((R*4+S)^(R&7)), slot j
__global__ void pack_wc_kernel(const float* __restrict__ W, u16* __restrict__ wcb) {
    int idx = blockIdx.x * 256 + threadIdx.x;   // 512*1024 elements
    int R = idx >> 10, k = idx & 1023;
    float val = W[(size_t)R * WSTRIDE + ND + k];
    int ks = k >> 5, S = (k >> 3) & 3, j = k & 7;
    int g = ((R << 2) + S) ^ (R & 7);           // granule 0..2047 (bijective)
    wcb[(ks << 14) + (g << 3) + j] = f2b(val);
}

// ---------------------------------------------------------------------------
// Kernel 1: h_proj[b][d] = bias[d] + sum_k hidden[b][k] * W_attn[d][k]  (f32 exact)
__global__ void hproj_kernel(const float* __restrict__ hidden, const float* __restrict__ W,
                             const float* __restrict__ bias, float* __restrict__ hp) {
    int b = blockIdx.x, d = threadIdx.x;   // 512 threads
    __shared__ float sh[ND];
    sh[d] = hidden[b * ND + d];
    __syncthreads();
    const float4* wr = (const float4*)(W + (size_t)d * WSTRIDE);
    float acc = bias[d];
#pragma unroll 8
    for (int k = 0; k < ND / 4; k++) {
        float4 w4 = wr[k];
        acc += w4.x * sh[4 * k] + w4.y * sh[4 * k + 1] + w4.z * sh[4 * k + 2] + w4.w * sh[4 * k + 3];
    }
    hp[b * ND + d] = acc;
}

// ---------------------------------------------------------------------------
// Kernel 2: fused c_proj GEMM (bf16 MFMA) + tanh + dot-v -> scores
// Block tile 128x512, BK=32, 512 threads / 8 waves (2Mx4N), wave tile 64x128.
// Double-buffered LDS + counted-vmcnt 2-phase pipeline (one s_barrier/iter,
// vmcnt never drained to 0 in the loop). A reg-staged 2 iters ahead (HBM
// latency ~900cy ~= 2 iters); B via global_load_lds from pre-swizzled pack.
__global__ __launch_bounds__(512, 2)
void fused_scores_kernel(const float* __restrict__ ctx, const u16* __restrict__ wcb,
                         const float* __restrict__ hp, const float* __restrict__ vvec,
                         float* __restrict__ scores) {
    __shared__ __align__(16) char lA[2][128 * 64];   // 2 x 8 KB
    __shared__ __align__(16) char lB[2][512 * 64];   // 2 x 32 KB
    __shared__ float shHp[ND];
    __shared__ float shV[ND];
    __shared__ float shSc[4][128];

    const int tid = threadIdx.x;
    const int blk = blockIdx.x;             // 1024 blocks
    const int b  = blk >> 5;                // 32 M-tiles per batch
    const int s0 = (blk & 31) << 7;

    shHp[tid] = hp[b * ND + tid];
    shV[tid]  = vvec[tid];

    const int lane = tid & 63, wid = tid >> 6;
    const int l15 = lane & 15, l4 = lane >> 4;
    const int wm = wid >> 2, wn = wid & 3;

    // A staging: thread -> row = tid>>2 (0..127), quad q = tid&3 (16B = 8 bf16)
    const int srow = tid >> 2, q = tid & 3;
    const float4* asrc = (const float4*)(ctx + (size_t)b * NS * NK + (size_t)(s0 + srow) * NK);
    const int awbyte = ((srow << 6) + (q << 4)) ^ ((srow & 7) << 4);

    // fragment LDS byte offsets (loop-invariant)
    int aoff[4], boff[8];
#pragma unroll
    for (int r = 0; r < 4; r++) {
        int row = (wm << 6) + (r << 4) + l15;
        aoff[r] = ((row << 6) + (l4 << 4)) ^ ((row & 7) << 4);
    }
#pragma unroll
    for (int c = 0; c < 8; c++) {
        int row = (wn << 7) + (c << 4) + l15;
        boff[c] = ((row << 6) + (l4 << 4)) ^ ((row & 7) << 4);
    }

    f32x4 acc[4][8];
    f32x4 zero = {0.f, 0.f, 0.f, 0.f};
#pragma unroll
    for (int r = 0; r < 4; r++)
#pragma unroll
        for (int c = 0; c < 8; c++) acc[r][c] = zero;

    const char* wcb_bytes = (const char*)wcb;
    float4 va0, va1;

    // ---- prologue: stage tile 0 into buf0, prefetch A(1) into regs ----
#pragma unroll
    for (int i = 0; i < 4; i++) {
        const char* src = wcb_bytes + ((((((wid << 2) + i) << 6) + lane)) << 4);
        __builtin_amdgcn_global_load_lds(
            (const __attribute__((address_space(1))) void*)src,
            (__attribute__((address_space(3))) void*)(&lB[0][((wid << 2) + i) << 10]),
            16, 0, 0);
    }
    va0 = asrc[q << 1];
    va1 = asrc[(q << 1) + 1];
    asm volatile("s_waitcnt vmcnt(0)" ::: "memory");
    {
        u16x8 a8;
        a8[0] = f2b(va0.x); a8[1] = f2b(va0.y); a8[2] = f2b(va0.z); a8[3] = f2b(va0.w);
        a8[4] = f2b(va1.x); a8[5] = f2b(va1.y); a8[6] = f2b(va1.z); a8[7] = f2b(va1.w);
        *(u16x8*)(&lA[0][awbyte]) = a8;
    }
    va0 = asrc[8 + (q << 1)];          // A(1)
    va1 = asrc[8 + (q << 1) + 1];
    asm volatile("s_waitcnt lgkmcnt(0)" ::: "memory");
    __builtin_amdgcn_s_barrier();
    __builtin_amdgcn_sched_barrier(0);

    // ---- main loop: invariant at top = exactly A(t+1)x2 outstanding ----
#pragma unroll 2
    for (int t = 0; t < NT; t++) {
        const int cur = t & 1, nxt = cur ^ 1;
        const int tB = (t + 1 < NT) ? t + 1 : NT - 1;   // clamp keeps counts uniform
        const int tA = (t + 2 < NT) ? t + 2 : NT - 1;

        // stage B(t+1) -> lB[nxt]  (4 x global_load_lds width-16, linear dest)
#pragma unroll
        for (int i = 0; i < 4; i++) {
            const char* src = wcb_bytes + ((size_t)tB << 15)
                              + (((((wid << 2) + i) << 6) + lane) << 4);
            __builtin_amdgcn_global_load_lds(
                (const __attribute__((address_space(1))) void*)src,
                (__attribute__((address_space(3))) void*)(&lB[nxt][((wid << 2) + i) << 10]),
                16, 0, 0);
        }
        // A(t+1) regs landed (4 younger B-lds still in flight)
        asm volatile("s_waitcnt vmcnt(4)" ::: "memory");
        {
            u16x8 a8;
            a8[0] = f2b(va0.x); a8[1] = f2b(va0.y); a8[2] = f2b(va0.z); a8[3] = f2b(va0.w);
            a8[4] = f2b(va1.x); a8[5] = f2b(va1.y); a8[6] = f2b(va1.z); a8[7] = f2b(va1.w);
            *(u16x8*)(&lA[nxt][awbyte]) = a8;
        }
        // prefetch A(t+2)
        va0 = asrc[(tA << 3) + (q << 1)];
        va1 = asrc[(tA << 3) + (q << 1) + 1];

        // compute on buf cur
        bf16x8 af[4], bfr[8];
#pragma unroll
        for (int r = 0; r < 4; r++) af[r] = *(const bf16x8*)(&lA[cur][aoff[r]]);
#pragma unroll
        for (int c = 0; c < 8; c++) bfr[c] = *(const bf16x8*)(&lB[cur][boff[c]]);
#pragma unroll
        for (int r = 0; r < 4; r++)
#pragma unroll
            for (int c = 0; c < 8; c++)
                acc[r][c] = __builtin_amdgcn_mfma_f32_16x16x32_bf16(af[r], bfr[c], acc[r][c], 0, 0, 0);

        // B(t+1) DMA + A ds_write done; A(t+2) stays in flight
        asm volatile("s_waitcnt vmcnt(2) lgkmcnt(0)" ::: "memory");
        __builtin_amdgcn_s_barrier();
        __builtin_amdgcn_sched_barrier(0);
    }

    // --- epilogue: tanh(c_proj + h_proj) . v , reduce over d ---
    // C/D: col = lane&15 (d), row = l4*4 + i (s within frag)
    float part[4][4];
#pragma unroll
    for (int r = 0; r < 4; r++)
#pragma unroll
        for (int i = 0; i < 4; i++) part[r][i] = 0.f;

#pragma unroll
    for (int r = 0; r < 4; r++) {
#pragma unroll
        for (int c = 0; c < 8; c++) {
            int d = (wn << 7) + (c << 4) + l15;
            float hpv = shHp[d], vv = shV[d];
#pragma unroll
            for (int i = 0; i < 4; i++) {
                float x = acc[r][c][i] + hpv;
                part[r][i] += fast_tanh(x) * vv;
            }
        }
    }

#pragma unroll
    for (int r = 0; r < 4; r++) {
#pragma unroll
        for (int i = 0; i < 4; i++) {
            float p = part[r][i];
            p += __shfl_xor(p, 1); p += __shfl_xor(p, 2);
            p += __shfl_xor(p, 4); p += __shfl_xor(p, 8);
            if (l15 == 0) shSc[wn][(wm << 6) + (r << 4) + (l4 << 2) + i] = p;
        }
    }
    __syncthreads();
    if (tid < 128) {
        float s = shSc[0][tid] + shSc[1][tid] + shSc[2][tid] + shSc[3][tid];
        scores[(size_t)b * NS + s0 + tid] = s;
    }
}

// ---------------------------------------------------------------------------
// Kernel 3: masked softmax over S per batch row, f32 output
__global__ void softmax_kernel(const float* __restrict__ scores, const int* __restrict__ mask,
                               float* __restrict__ out) {
    int b = blockIdx.x, tid = threadIdx.x;   // 256 threads, 16 elems each
    __shared__ float red[256];
    float loc[16];
    float mx = -INFINITY;
#pragma unroll
    for (int i = 0; i < 16; i++) {
        int idx = i * 256 + tid;
        float s = scores[b * NS + idx];
        if (mask[b * NS + idx] == 0) s = -INFINITY;
        loc[i] = s;
        mx = fmaxf(mx, s);
    }
    red[tid] = mx; __syncthreads();
    for (int off = 128; off; off >>= 1) { if (tid < off) red[tid] = fmaxf(red[tid], red[tid + off]); __syncthreads(); }
    mx = red[0]; __syncthreads();
    float sum = 0.f;
#pragma unroll
    for (int i = 0; i < 16; i++) { float e = __expf(loc[i] - mx); loc[i] = e; sum += e; }
    red[tid] = sum; __syncthreads();
    for (int off = 128; off; off >>= 1) { if (tid < off) red[tid] += red[tid + off]; __syncthreads(); }
    float inv = 1.f / red[0];
#pragma unroll
    for (int i = 0; i < 16; i++) out[b * NS + i * 256 + tid] = loc[i] * inv;
}

// ---------------------------------------------------------------------------
extern "C" void kernel_launch(void* const* d_in, const int* in_sizes, int n_in,
                              void* d_out, int out_size, void* d_ws, size_t ws_size,
                              hipStream_t stream) {
    const float* hidden  = (const float*)d_in[0];
    const float* context = (const float*)d_in[1];
    const int*   mask    = (const int*)d_in[2];
    const float* W_attn  = (const float*)d_in[3];
    const float* b_attn  = (const float*)d_in[4];
    const float* v       = (const float*)d_in[5];
    float* out           = (float*)d_out;

    char* ws = (char*)d_ws;
    u16*   wcb    = (u16*)ws;                   // 1 MB
    float* hp     = (float*)(ws + (1 << 20));   // 64 KB
    float* scores = (float*)(ws + (1 << 20) + (64 << 10));  // 512 KB

    pack_wc_kernel<<<2048, 256, 0, stream>>>(W_attn, wcb);
    hproj_kernel<<<NB, ND, 0, stream>>>(hidden, W_attn, b_attn, hp);
    fused_scores_kernel<<<NB * 32, 512, 0, stream>>>(context, wcb, hp, v, scores);
    softmax_kernel<<<NB, 256, 0, stream>>>(scores, mask, out);
}